// Round 4
// baseline (707.819 us; speedup 1.0000x reference)
//
#include <hip/hip_runtime.h>

#define NIN 512
#define NOUT 256
#define NPART 8   // XCD count; edge partition s = (i>>8)&7 == blockIdx&7

typedef __attribute__((ext_vector_type(8))) __bf16 bf16x8;
typedef __attribute__((ext_vector_type(4))) float f32x4;

__device__ __forceinline__ ushort f2bf(float f) {
  uint u = __builtin_bit_cast(uint, f);
  uint r = (u + 0x7FFFu + ((u >> 16) & 1u)) >> 16;  // RNE
  return (ushort)r;
}
__device__ __forceinline__ uint pk2(float a, float b) {
  return (uint)f2bf(a) | ((uint)f2bf(b) << 16);
}
__device__ __forceinline__ float bf2f(ushort u) {
  return __builtin_bit_cast(float, (uint)u << 16);
}

// ---------------- GEMM: h[M][256] = bf16(x[M][512] @ W[256][512]^T + b) ----
__global__ __launch_bounds__(512) void gemm_kernel(
    const float* __restrict__ x, const float* __restrict__ W,
    const float* __restrict__ bias, ushort* __restrict__ h, int M) {
  __shared__ ushort a_lds[128 * 40];  // [row][k] stride 40
  __shared__ ushort b_lds[256 * 40];  // [n][k]   stride 40

  const int t = threadIdx.x;
  const int l = t & 63;
  const int wv = t >> 6;
  const int m0 = blockIdx.x * 128;

  const int lrow = l & 15;
  const int lk = (l >> 4) * 8;

  f32x4 acc[16];
#pragma unroll
  for (int i = 0; i < 16; ++i) acc[i] = (f32x4){0.f, 0.f, 0.f, 0.f};

  float biasr[16];
#pragma unroll
  for (int nt = 0; nt < 16; ++nt) biasr[nt] = bias[nt * 16 + lrow];

  const int arow = t >> 2;
  const int akc = (t & 3) * 8;
  const int brow = t >> 1;
  const int bkc = (t & 1) * 16;

  for (int k0 = 0; k0 < NIN; k0 += 32) {
    {
      float4 v0 = make_float4(0.f, 0.f, 0.f, 0.f), v1 = v0;
      if (m0 + arow < M) {
        const float4* xs =
            reinterpret_cast<const float4*>(x + (size_t)(m0 + arow) * NIN + k0 + akc);
        v0 = xs[0];
        v1 = xs[1];
      }
      uint4 p;
      p.x = pk2(v0.x, v0.y); p.y = pk2(v0.z, v0.w);
      p.z = pk2(v1.x, v1.y); p.w = pk2(v1.z, v1.w);
      *reinterpret_cast<uint4*>(&a_lds[arow * 40 + akc]) = p;
    }
    {
      const float4* wsrc =
          reinterpret_cast<const float4*>(W + (size_t)brow * NIN + k0 + bkc);
      float4 w0 = wsrc[0], w1 = wsrc[1], w2 = wsrc[2], w3 = wsrc[3];
      uint4 p0, p1;
      p0.x = pk2(w0.x, w0.y); p0.y = pk2(w0.z, w0.w);
      p0.z = pk2(w1.x, w1.y); p0.w = pk2(w1.z, w1.w);
      p1.x = pk2(w2.x, w2.y); p1.y = pk2(w2.z, w2.w);
      p1.z = pk2(w3.x, w3.y); p1.w = pk2(w3.z, w3.w);
      *reinterpret_cast<uint4*>(&b_lds[brow * 40 + bkc]) = p0;
      *reinterpret_cast<uint4*>(&b_lds[brow * 40 + bkc + 8]) = p1;
    }
    __syncthreads();

    bf16x8 af = *reinterpret_cast<const bf16x8*>(&a_lds[(wv * 16 + lrow) * 40 + lk]);
#pragma unroll
    for (int nt = 0; nt < 16; ++nt) {
      bf16x8 bf_ = *reinterpret_cast<const bf16x8*>(&b_lds[(nt * 16 + lrow) * 40 + lk]);
      acc[nt] = __builtin_amdgcn_mfma_f32_16x16x32_bf16(af, bf_, acc[nt], 0, 0, 0);
    }
    __syncthreads();
  }

  const int mbase = m0 + wv * 16 + (l >> 4) * 4;
#pragma unroll
  for (int r = 0; r < 4; ++r) {
    int m = mbase + r;
    if (m >= M) continue;
#pragma unroll
    for (int nt = 0; nt < 16; ++nt)
      h[(size_t)m * NOUT + nt * 16 + lrow] = f2bf(acc[nt][r] + biasr[nt]);
  }
}

// ---------------- CSR build: partitioned histogram --------------------------
// offs layout: [NPART][M] partition-major; partition s = (i>>8)&7 so that
// all edges of partition s are processed by blocks b ≡ s (mod 8) -> one XCD.
__global__ __launch_bounds__(256) void hist_kernel(
    const int* __restrict__ rows, int* __restrict__ offs, int E, int M) {
  int i = blockIdx.x * blockDim.x + threadIdx.x;
  int stride = gridDim.x * blockDim.x;
  for (; i < E; i += stride) {
    int s = (i >> 8) & (NPART - 1);
    atomicAdd(&offs[s * M + rows[i]], 1);
  }
}

// ---------------- exclusive scan (hierarchical) ------------------------------
__global__ __launch_bounds__(256) void scanA_kernel(
    int* __restrict__ data, int* __restrict__ blockSums, int n) {
  __shared__ int s[256];
  const int t = threadIdx.x;
  const int base = blockIdx.x * 1024 + t * 4;
  int v[4];
#pragma unroll
  for (int j = 0; j < 4; ++j) v[j] = (base + j < n) ? data[base + j] : 0;
  int local = v[0] + v[1] + v[2] + v[3];
  s[t] = local;
  __syncthreads();
  for (int off = 1; off < 256; off <<= 1) {
    int x = (t >= off) ? s[t - off] : 0;
    __syncthreads();
    s[t] += x;
    __syncthreads();
  }
  int excl = s[t] - local;
  if (t == 255 && blockSums) blockSums[blockIdx.x] = s[255];
  int run = excl;
#pragma unroll
  for (int j = 0; j < 4; ++j) {
    int nv = v[j];
    if (base + j < n) data[base + j] = run;
    run += nv;
  }
}

__global__ __launch_bounds__(256) void scanC_kernel(
    int* __restrict__ data, const int* __restrict__ blockSums, int n) {
  int i = blockIdx.x * blockDim.x + threadIdx.x;
  if (i < n) data[i] += blockSums[i >> 10];
}

// ---------------- placement: (col,val) pairs, XCD-partitioned ----------------
__global__ __launch_bounds__(256) void place_kernel(
    const int* __restrict__ rows, const int* __restrict__ cols,
    const float* __restrict__ vals, int* __restrict__ offs,
    int2* __restrict__ sev, int E, int M) {
  int i = blockIdx.x * blockDim.x + threadIdx.x;
  int stride = gridDim.x * blockDim.x;
  for (; i < E; i += stride) {
    int s = (i >> 8) & (NPART - 1);
    int r = rows[i];
    int pos = atomicAdd(&offs[s * M + r], 1);
    int2 p;
    p.x = cols[i];
    p.y = __builtin_bit_cast(int, vals[i]);
    sev[pos] = p;
  }
}

// ---------------- gather-reduce: one wave per output row --------------------
__global__ __launch_bounds__(256) void accum_kernel(
    const ushort* __restrict__ h, const int2* __restrict__ sev,
    const int* __restrict__ offs, float* __restrict__ out, int M) {
  int wid = (int)((blockIdx.x * (size_t)blockDim.x + threadIdx.x) >> 6);
  if (wid >= M) return;
  const int lane = threadIdx.x & 63;

  float4 acc = make_float4(0.f, 0.f, 0.f, 0.f);
#pragma unroll
  for (int s = 0; s < NPART; ++s) {
    int p = s * M + wid;
    int e = (p == 0) ? 0 : offs[p - 1];
    int end = offs[p];
    for (; e + 1 < end; e += 2) {
      int2 e0 = sev[e], e1 = sev[e + 1];
      float v0 = __builtin_bit_cast(float, e0.y);
      float v1 = __builtin_bit_cast(float, e1.y);
      ushort4 h0 = *reinterpret_cast<const ushort4*>(h + (size_t)e0.x * NOUT + lane * 4);
      ushort4 h1 = *reinterpret_cast<const ushort4*>(h + (size_t)e1.x * NOUT + lane * 4);
      acc.x += v0 * bf2f(h0.x); acc.y += v0 * bf2f(h0.y);
      acc.z += v0 * bf2f(h0.z); acc.w += v0 * bf2f(h0.w);
      acc.x += v1 * bf2f(h1.x); acc.y += v1 * bf2f(h1.y);
      acc.z += v1 * bf2f(h1.z); acc.w += v1 * bf2f(h1.w);
    }
    if (e < end) {
      int2 e0 = sev[e];
      float v0 = __builtin_bit_cast(float, e0.y);
      ushort4 h0 = *reinterpret_cast<const ushort4*>(h + (size_t)e0.x * NOUT + lane * 4);
      acc.x += v0 * bf2f(h0.x); acc.y += v0 * bf2f(h0.y);
      acc.z += v0 * bf2f(h0.z); acc.w += v0 * bf2f(h0.w);
    }
  }
  *reinterpret_cast<float4*>(out + (size_t)wid * NOUT + lane * 4) = acc;
}

extern "C" void kernel_launch(void* const* d_in, const int* in_sizes, int n_in,
                              void* d_out, int out_size, void* d_ws, size_t ws_size,
                              hipStream_t stream) {
  const float* x        = (const float*)d_in[0];
  const int*   adj_rows = (const int*)d_in[1];
  const int*   adj_cols = (const int*)d_in[2];
  const float* adj_vals = (const float*)d_in[3];
  const float* W        = (const float*)d_in[4];
  const float* b        = (const float*)d_in[5];
  float* out = (float*)d_out;

  const int M = in_sizes[0] / NIN;   // 100000
  const int E = in_sizes[1];         // 3200000

  // workspace layout
  ushort* h = (ushort*)d_ws;                       // M*NOUT bf16 (51.2 MB)
  int2*   sev = (int2*)(h + (size_t)M * NOUT);     // E int2 (25.6 MB)
  int*    offs = (int*)(sev + E);                  // NPART*M ints (3.2 MB)
  const int nOffs = NPART * M;
  const int scanBlocks = (nOffs + 1023) / 1024;    // 782
  int*    blockSums = offs + nOffs;                // scanBlocks ints

  gemm_kernel<<<(M + 127) / 128, 512, 0, stream>>>(x, W, b, h, M);

  hipMemsetAsync(offs, 0, (size_t)(nOffs + scanBlocks + 8) * sizeof(int), stream);
  hist_kernel<<<2048, 256, 0, stream>>>(adj_rows, offs, E, M);
  scanA_kernel<<<scanBlocks, 256, 0, stream>>>(offs, blockSums, nOffs);
  scanA_kernel<<<1, 256, 0, stream>>>(blockSums, nullptr, scanBlocks);
  scanC_kernel<<<(nOffs + 255) / 256, 256, 0, stream>>>(offs, blockSums, nOffs);
  place_kernel<<<2048, 256, 0, stream>>>(adj_rows, adj_cols, adj_vals, offs,
                                         sev, E, M);
  int ablocks = (int)(((size_t)M * 64 + 255) / 256);
  accum_kernel<<<ablocks, 256, 0, stream>>>(h, sev, offs, out, M);
}

// Round 5
// 696.486 us; speedup vs baseline: 1.0163x; 1.0163x over previous
//
#include <hip/hip_runtime.h>

#define NIN 512
#define NOUT 256
#define NPART 8

typedef __attribute__((ext_vector_type(8))) __bf16 bf16x8;
typedef __attribute__((ext_vector_type(4))) float f32x4;

__device__ __forceinline__ ushort f2bf(float f) {
  uint u = __builtin_bit_cast(uint, f);
  uint r = (u + 0x7FFFu + ((u >> 16) & 1u)) >> 16;  // RNE
  return (ushort)r;
}
__device__ __forceinline__ uint pk2(float a, float b) {
  return (uint)f2bf(a) | ((uint)f2bf(b) << 16);
}
__device__ __forceinline__ float bf2f(ushort u) {
  return __builtin_bit_cast(float, (uint)u << 16);
}

// ---------------- GEMM + fused histogram -----------------------------------
// h[M][256] = bf16(x @ W^T + b). 512 thr = 8 waves in 2x4; 64x64 per wave.
// Fused: grid-stride histogram of adj_rows into cnt[s*M+r], s = blockIdx&7
// (same chunking as place_kernel below -> counts match cursors).
__global__ __launch_bounds__(512) void gemm_hist_kernel(
    const float* __restrict__ x, const float* __restrict__ W,
    const float* __restrict__ bias, ushort* __restrict__ h, int M,
    const int* __restrict__ rows, int* __restrict__ cnt, int E) {
  __shared__ ushort a_lds[128 * 40];  // [row][k] stride 40
  __shared__ ushort b_lds[256 * 40];  // [n][k]   stride 40

  const int t = threadIdx.x;
  const int l = t & 63;
  const int wv = t >> 6;
  const int wr = wv >> 2;     // 0..1  (64-row block)
  const int wc = wv & 3;      // 0..3  (64-col block)
  const int m0 = blockIdx.x * 128;

  const int lrow = l & 15;
  const int lk = (l >> 4) * 8;

  f32x4 acc[4][4];
#pragma unroll
  for (int i = 0; i < 4; ++i)
#pragma unroll
    for (int j = 0; j < 4; ++j) acc[i][j] = (f32x4){0.f, 0.f, 0.f, 0.f};

  float biasr[4];
#pragma unroll
  for (int j = 0; j < 4; ++j) biasr[j] = bias[wc * 64 + j * 16 + lrow];

  const int arow = t >> 2;
  const int akc = (t & 3) * 8;
  const int brow = t >> 1;
  const int bkc = (t & 1) * 16;

  for (int k0 = 0; k0 < NIN; k0 += 32) {
    {
      float4 v0 = make_float4(0.f, 0.f, 0.f, 0.f), v1 = v0;
      if (m0 + arow < M) {
        const float4* xs =
            reinterpret_cast<const float4*>(x + (size_t)(m0 + arow) * NIN + k0 + akc);
        v0 = xs[0];
        v1 = xs[1];
      }
      uint4 p;
      p.x = pk2(v0.x, v0.y); p.y = pk2(v0.z, v0.w);
      p.z = pk2(v1.x, v1.y); p.w = pk2(v1.z, v1.w);
      *reinterpret_cast<uint4*>(&a_lds[arow * 40 + akc]) = p;
    }
    {
      const float4* wsrc =
          reinterpret_cast<const float4*>(W + (size_t)brow * NIN + k0 + bkc);
      float4 w0 = wsrc[0], w1 = wsrc[1], w2 = wsrc[2], w3 = wsrc[3];
      uint4 p0, p1;
      p0.x = pk2(w0.x, w0.y); p0.y = pk2(w0.z, w0.w);
      p0.z = pk2(w1.x, w1.y); p0.w = pk2(w1.z, w1.w);
      p1.x = pk2(w2.x, w2.y); p1.y = pk2(w2.z, w2.w);
      p1.z = pk2(w3.x, w3.y); p1.w = pk2(w3.z, w3.w);
      *reinterpret_cast<uint4*>(&b_lds[brow * 40 + bkc]) = p0;
      *reinterpret_cast<uint4*>(&b_lds[brow * 40 + bkc + 8]) = p1;
    }
    __syncthreads();

    bf16x8 af[4], bf_[4];
#pragma unroll
    for (int i = 0; i < 4; ++i)
      af[i] = *reinterpret_cast<const bf16x8*>(
          &a_lds[(wr * 64 + i * 16 + lrow) * 40 + lk]);
#pragma unroll
    for (int j = 0; j < 4; ++j)
      bf_[j] = *reinterpret_cast<const bf16x8*>(
          &b_lds[(wc * 64 + j * 16 + lrow) * 40 + lk]);
#pragma unroll
    for (int i = 0; i < 4; ++i)
#pragma unroll
      for (int j = 0; j < 4; ++j)
        acc[i][j] = __builtin_amdgcn_mfma_f32_16x16x32_bf16(af[i], bf_[j],
                                                            acc[i][j], 0, 0, 0);
    __syncthreads();
  }

  // epilogue
#pragma unroll
  for (int i = 0; i < 4; ++i) {
    const int mbase = m0 + wr * 64 + i * 16 + (l >> 4) * 4;
#pragma unroll
    for (int r = 0; r < 4; ++r) {
      int m = mbase + r;
      if (m >= M) continue;
#pragma unroll
      for (int j = 0; j < 4; ++j)
        h[(size_t)m * NOUT + wc * 64 + j * 16 + lrow] =
            f2bf(acc[i][j][r] + biasr[j]);
    }
  }

  // ---- fused histogram (overlaps other blocks' compute) ----
  const int s = blockIdx.x & (NPART - 1);
  const int stride = gridDim.x * 512;
  for (int i = blockIdx.x * 512 + t; i < E; i += stride)
    atomicAdd(&cnt[s * M + rows[i]], 1);
}

// ---------------- exclusive scan (hierarchical) ------------------------------
__global__ __launch_bounds__(256) void scanA_kernel(
    int* __restrict__ data, int* __restrict__ blockSums, int n) {
  __shared__ int s[256];
  const int t = threadIdx.x;
  const int base = blockIdx.x * 1024 + t * 4;
  int v[4];
#pragma unroll
  for (int j = 0; j < 4; ++j) v[j] = (base + j < n) ? data[base + j] : 0;
  int local = v[0] + v[1] + v[2] + v[3];
  s[t] = local;
  __syncthreads();
  for (int off = 1; off < 256; off <<= 1) {
    int x = (t >= off) ? s[t - off] : 0;
    __syncthreads();
    s[t] += x;
    __syncthreads();
  }
  int excl = s[t] - local;
  if (t == 255 && blockSums) blockSums[blockIdx.x] = s[255];
  int run = excl;
#pragma unroll
  for (int j = 0; j < 4; ++j) {
    int nv = v[j];
    if (base + j < n) data[base + j] = run;
    run += nv;
  }
}

__global__ __launch_bounds__(256) void scanC_kernel(
    int* __restrict__ data, const int* __restrict__ blockSums, int n) {
  int i = blockIdx.x * blockDim.x + threadIdx.x;
  if (i < n) data[i] += blockSums[i >> 10];
}

// ---------------- bnds: transpose per-row segment bounds --------------------
// bnds[r][s] = offs[s*M+r] (start of segment (s,r)); row r's ends are
// bnds[r+1][s]. bnds has M+1 rows of 8 ints (32 B).
__global__ __launch_bounds__(256) void bnds_kernel(
    const int* __restrict__ offs, int* __restrict__ bnds, int M, int E) {
  __shared__ int lds[NPART][257];
  const int t = threadIdx.x;
  const int r = blockIdx.x * 256 + t;
#pragma unroll
  for (int s = 0; s < NPART; ++s) {
    int v = 0;
    if (r <= M) {
      size_t idx = (size_t)s * M + r;
      v = (idx < (size_t)NPART * M) ? offs[idx] : E;
    }
    lds[s][t] = v;
  }
  __syncthreads();
  if (r <= M) {
    int4 lo, hi;
    lo.x = lds[0][t]; lo.y = lds[1][t]; lo.z = lds[2][t]; lo.w = lds[3][t];
    hi.x = lds[4][t]; hi.y = lds[5][t]; hi.z = lds[6][t]; hi.w = lds[7][t];
    *reinterpret_cast<int4*>(bnds + (size_t)r * 8) = lo;
    *reinterpret_cast<int4*>(bnds + (size_t)r * 8 + 4) = hi;
  }
}

// ---------------- placement: (col,val) pairs, XCD-partitioned ----------------
// MUST use the same grid/block/chunking as gemm_hist's fused histogram.
__global__ __launch_bounds__(512) void place_kernel(
    const int* __restrict__ rows, const int* __restrict__ cols,
    const float* __restrict__ vals, int* __restrict__ offs,
    int2* __restrict__ sev, int E, int M) {
  const int s = blockIdx.x & (NPART - 1);
  const int stride = gridDim.x * 512;
  for (int i = blockIdx.x * 512 + threadIdx.x; i < E; i += stride) {
    int r = rows[i];
    int pos = atomicAdd(&offs[s * M + r], 1);
    int2 p;
    p.x = cols[i];
    p.y = __builtin_bit_cast(int, vals[i]);
    sev[pos] = p;
  }
}

// ---------------- gather-reduce: one wave per output row --------------------
__global__ __launch_bounds__(256) void accum_kernel(
    const ushort* __restrict__ h, const int2* __restrict__ sev,
    const int* __restrict__ bnds, float* __restrict__ out, int M) {
  int wid = (int)((blockIdx.x * (size_t)blockDim.x + threadIdx.x) >> 6);
  if (wid >= M) return;
  const int lane = threadIdx.x & 63;

  // one 64B line: starts (this row) + ends (next row's starts)
  int4 sa = *reinterpret_cast<const int4*>(bnds + (size_t)wid * 8);
  int4 sb = *reinterpret_cast<const int4*>(bnds + (size_t)wid * 8 + 4);
  int4 ea = *reinterpret_cast<const int4*>(bnds + (size_t)wid * 8 + 8);
  int4 eb = *reinterpret_cast<const int4*>(bnds + (size_t)wid * 8 + 12);
  int starts[8] = {sa.x, sa.y, sa.z, sa.w, sb.x, sb.y, sb.z, sb.w};
  int ends[8]   = {ea.x, ea.y, ea.z, ea.w, eb.x, eb.y, eb.z, eb.w};

  float4 acc = make_float4(0.f, 0.f, 0.f, 0.f);
#pragma unroll
  for (int s = 0; s < NPART; ++s) {
    int e = starts[s];
    const int end = ends[s];
    for (; e + 3 < end; e += 4) {
      int2 e0 = sev[e], e1 = sev[e + 1], e2 = sev[e + 2], e3 = sev[e + 3];
      float v0 = __builtin_bit_cast(float, e0.y);
      float v1 = __builtin_bit_cast(float, e1.y);
      float v2 = __builtin_bit_cast(float, e2.y);
      float v3 = __builtin_bit_cast(float, e3.y);
      ushort4 h0 = *reinterpret_cast<const ushort4*>(h + (size_t)e0.x * NOUT + lane * 4);
      ushort4 h1 = *reinterpret_cast<const ushort4*>(h + (size_t)e1.x * NOUT + lane * 4);
      ushort4 h2 = *reinterpret_cast<const ushort4*>(h + (size_t)e2.x * NOUT + lane * 4);
      ushort4 h3 = *reinterpret_cast<const ushort4*>(h + (size_t)e3.x * NOUT + lane * 4);
      acc.x += v0 * bf2f(h0.x); acc.y += v0 * bf2f(h0.y);
      acc.z += v0 * bf2f(h0.z); acc.w += v0 * bf2f(h0.w);
      acc.x += v1 * bf2f(h1.x); acc.y += v1 * bf2f(h1.y);
      acc.z += v1 * bf2f(h1.z); acc.w += v1 * bf2f(h1.w);
      acc.x += v2 * bf2f(h2.x); acc.y += v2 * bf2f(h2.y);
      acc.z += v2 * bf2f(h2.z); acc.w += v2 * bf2f(h2.w);
      acc.x += v3 * bf2f(h3.x); acc.y += v3 * bf2f(h3.y);
      acc.z += v3 * bf2f(h3.z); acc.w += v3 * bf2f(h3.w);
    }
    for (; e < end; ++e) {
      int2 e0 = sev[e];
      float v0 = __builtin_bit_cast(float, e0.y);
      ushort4 h0 = *reinterpret_cast<const ushort4*>(h + (size_t)e0.x * NOUT + lane * 4);
      acc.x += v0 * bf2f(h0.x); acc.y += v0 * bf2f(h0.y);
      acc.z += v0 * bf2f(h0.z); acc.w += v0 * bf2f(h0.w);
    }
  }
  *reinterpret_cast<float4*>(out + (size_t)wid * NOUT + lane * 4) = acc;
}

extern "C" void kernel_launch(void* const* d_in, const int* in_sizes, int n_in,
                              void* d_out, int out_size, void* d_ws, size_t ws_size,
                              hipStream_t stream) {
  const float* x        = (const float*)d_in[0];
  const int*   adj_rows = (const int*)d_in[1];
  const int*   adj_cols = (const int*)d_in[2];
  const float* adj_vals = (const float*)d_in[3];
  const float* W        = (const float*)d_in[4];
  const float* b        = (const float*)d_in[5];
  float* out = (float*)d_out;

  const int M = in_sizes[0] / NIN;   // 100000
  const int E = in_sizes[1];         // 3200000

  // workspace layout (all 16B-aligned)
  ushort* h = (ushort*)d_ws;                       // M*NOUT bf16 (51.2 MB)
  int2*   sev = (int2*)(h + (size_t)M * NOUT);     // E int2 (25.6 MB)
  int*    offs = (int*)(sev + E);                  // NPART*M ints (3.2 MB)
  const int nOffs = NPART * M;
  const int scanBlocks = (nOffs + 1023) / 1024;    // 782
  int*    blockSums = offs + nOffs;                // scanBlocks ints
  int*    bnds = blockSums + 1024;                 // (M+1)*8 ints (3.2 MB)

  const int gblocks = (M + 127) / 128;             // 782 — shared by gemm & place

  hipMemsetAsync(offs, 0, (size_t)(nOffs + 1024) * sizeof(int), stream);
  gemm_hist_kernel<<<gblocks, 512, 0, stream>>>(x, W, b, h, M, adj_rows, offs, E);
  scanA_kernel<<<scanBlocks, 256, 0, stream>>>(offs, blockSums, nOffs);
  scanA_kernel<<<1, 256, 0, stream>>>(blockSums, nullptr, scanBlocks);
  scanC_kernel<<<(nOffs + 255) / 256, 256, 0, stream>>>(offs, blockSums, nOffs);
  bnds_kernel<<<(M + 256) / 256, 256, 0, stream>>>(offs, bnds, M, E);
  place_kernel<<<gblocks, 512, 0, stream>>>(adj_rows, adj_cols, adj_vals, offs,
                                            sev, E, M);
  int ablocks = (int)(((size_t)M * 64 + 255) / 256);
  accum_kernel<<<ablocks, 256, 0, stream>>>(h, sev, bnds, out, M);
}